// Round 6
// baseline (516.108 us; speedup 1.0000x reference)
//
#include <hip/hip_runtime.h>
#include <cstdint>
#include <cstddef>

#define NB2 2048            // duration buckets (uniform [0,1))
#define NCELL (NB2 * 4)     // buckets x 4 causes
#define NPART 8             // one partial histogram per XCD-ish slice (blockIdx & 7)
#define ALPHA 0.4
#define EPS 1e-8

// Workspace layout:
//   [0,128)     double acc[9]: [0..3] sum eta over events/cause, [4..7] sum log(denom)/cause, [8] CE sum
//   [128,144)   uint cnt[4]
//   [192,196)   uint ticket (ce completion counter)
//   [4096, 4096+8*32KB)  float partial[8][NCELL] (AoS: [b*4+c]), atomically accumulated
//   then 32KB            float suffix[NCELL] (AoS)

#define WRED(v) { for (int o = 32; o; o >>= 1) v += __shfl_down(v, o); }

typedef float vf4 __attribute__((ext_vector_type(4)));
static __device__ __forceinline__ float4 ntload4(const float4* p) {
  vf4 v = __builtin_nontemporal_load((const vf4*)p);
  return make_float4(v.x, v.y, v.z, v.w);
}

// ---------------- Cox pass: eta, exp, histogram, event sums ----------------
// 512 thr x 1024 blocks; scattered per-lane float4 loads (measured-best pattern),
// nontemporal on the 128 MB log_h stream.
__global__ __launch_bounds__(512, 8) void cox_kernel(
    const float* __restrict__ log_h, const float* __restrict__ dur,
    const int* __restrict__ ev, float* __restrict__ partial,
    double* __restrict__ acc, unsigned int* __restrict__ cnt, int N)
{
  __shared__ float h[NCELL];          // 32 KB private histogram, SoA
  __shared__ float s_f[4];
  __shared__ unsigned int s_u[4];
  const int t = threadIdx.x;
  for (int j = t; j < NCELL; j += 512) h[j] = 0.f;
  if (t < 4) { s_f[t] = 0.f; s_u[t] = 0u; }
  __syncthreads();

  float ea0 = 0.f, ea1 = 0.f, ea2 = 0.f, ea3 = 0.f;
  int c0 = 0, c1 = 0, c2 = 0, c3 = 0;

  const int stride = gridDim.x * 512;
  for (int i = blockIdx.x * 512 + t; i < N; i += stride) {
    const float4* ph = (const float4*)(log_h + (size_t)i * 32);
    float m0 = 0.f, m1 = 0.f, m2 = 0.f, m3 = 0.f;
#pragma unroll
    for (int m = 0; m < 8; ++m) {
      float4 v = ntload4(ph + m);
      m0 += v.x; m1 += v.y; m2 += v.z; m3 += v.w;
    }
    float e0 = fminf(fmaxf(m0 * 0.125f, -50.f), 50.f);
    float e1 = fminf(fmaxf(m1 * 0.125f, -50.f), 50.f);
    float e2 = fminf(fmaxf(m2 * 0.125f, -50.f), 50.f);
    float e3 = fminf(fmaxf(m3 * 0.125f, -50.f), 50.f);
    float x0 = __expf(e0), x1 = __expf(e1), x2 = __expf(e2), x3 = __expf(e3);

    float d = dur[i];
    int e = ev[i];
    int b = (int)(d * (float)NB2);
    b = b < 0 ? 0 : (b > NB2 - 1 ? NB2 - 1 : b);
    atomicAdd(&h[0 * NB2 + b], x0);   // SoA: conflict-light
    atomicAdd(&h[1 * NB2 + b], x1);
    atomicAdd(&h[2 * NB2 + b], x2);
    atomicAdd(&h[3 * NB2 + b], x3);

    ea0 += (e == 1) ? e0 : 0.f;  c0 += (e == 1);
    ea1 += (e == 2) ? e1 : 0.f;  c1 += (e == 2);
    ea2 += (e == 3) ? e2 : 0.f;  c2 += (e == 3);
    ea3 += (e == 4) ? e3 : 0.f;  c3 += (e == 4);
  }

  WRED(ea0) WRED(ea1) WRED(ea2) WRED(ea3)
  WRED(c0) WRED(c1) WRED(c2) WRED(c3)
  if ((t & 63) == 0) {
    atomicAdd(&s_f[0], ea0); atomicAdd(&s_f[1], ea1);
    atomicAdd(&s_f[2], ea2); atomicAdd(&s_f[3], ea3);
    atomicAdd(&s_u[0], (unsigned)c0); atomicAdd(&s_u[1], (unsigned)c1);
    atomicAdd(&s_u[2], (unsigned)c2); atomicAdd(&s_u[3], (unsigned)c3);
  }
  __syncthreads();

  // Flush LDS histogram (SoA) into partial[blockIdx&7] (AoS) with atomics.
  float* part = partial + (size_t)(blockIdx.x & (NPART - 1)) * NCELL;
  const int rot = ((blockIdx.x >> 3) & 31) * 256;
  for (int j = t; j < NCELL; j += 512) {
    int jj = (j + rot) & (NCELL - 1);
    float v = h[((jj & 3) << 11) + (jj >> 2)];   // SoA read -> AoS cell jj
    unsafeAtomicAdd(&part[jj], v);
  }

  if (t < 4) {
    unsafeAtomicAdd(&acc[t], (double)s_f[t]);
    atomicAdd(&cnt[t], s_u[t]);
  }
}

// ---- Inclusive suffix-sum over NB2 buckets (4 causes packed as float4). ----
// Also folds the NPART partial histograms. One WG.
__global__ __launch_bounds__(1024) void scan_kernel(
    const float* __restrict__ partial, float* __restrict__ suffix)
{
  const int CH = NB2 / 1024;   // 2
  const int t = threadIdx.x;
  __shared__ float4 part[1024];
  float4* out = (float4*)suffix;

  float4 loc[CH];
  float4 a = make_float4(0.f, 0.f, 0.f, 0.f);
  for (int j = 0; j < CH; ++j) {
    float4 s = make_float4(0.f, 0.f, 0.f, 0.f);
#pragma unroll
    for (int p = 0; p < NPART; ++p) {
      float4 v = ((const float4*)(partial + (size_t)p * NCELL))[t * CH + j];
      s.x += v.x; s.y += v.y; s.z += v.z; s.w += v.w;
    }
    loc[j] = s;
    a.x += s.x; a.y += s.y; a.z += s.z; a.w += s.w;
  }
  part[t] = a;
  __syncthreads();
  for (int off = 1; off < 1024; off <<= 1) {
    float4 add = make_float4(0.f, 0.f, 0.f, 0.f);
    if (t + off < 1024) add = part[t + off];
    __syncthreads();
    float4 cur = part[t];
    cur.x += add.x; cur.y += add.y; cur.z += add.z; cur.w += add.w;
    part[t] = cur;
    __syncthreads();
  }
  float4 carry = (t < 1023) ? part[t + 1] : make_float4(0.f, 0.f, 0.f, 0.f);
  for (int j = CH - 1; j >= 0; --j) {
    carry.x += loc[j].x; carry.y += loc[j].y; carry.z += loc[j].z; carry.w += loc[j].w;
    out[t * CH + j] = carry;
  }
}

// -------- CE + log(denom) gather + fused finalize (ticket) --------
// Streams logits (160 MB) nontemporally; scattered per-lane pattern (measured-best).
__global__ __launch_bounds__(256, 6) void ce_kernel(
    const float* __restrict__ logits, const int* __restrict__ lab,
    const float* __restrict__ dur, const int* __restrict__ ev,
    const float* __restrict__ suffix, double* __restrict__ acc,
    const unsigned int* __restrict__ cnt, unsigned int* __restrict__ ticket,
    float* __restrict__ out, int N)
{
  __shared__ float s_f[5];   // [0..3] sum log(denom)/cause, [4] CE
  const int t = threadIdx.x;
  if (t < 5) s_f[t] = 0.f;
  __syncthreads();

  float ce = 0.f, lg0 = 0.f, lg1 = 0.f, lg2 = 0.f, lg3 = 0.f;
  const int stride = gridDim.x * 256;
  for (int i = blockIdx.x * 256 + t; i < N; i += stride) {
    const float4* pl = (const float4*)(logits + (size_t)i * 40);
    int lb = lab[i];
    int e = ev[i];
    float d = dur[i];
    float l0, l1, l2, l3, l4;
    {
      // 10 NT float4 loads; each element consumed once -> folds into adds.
      float4 v0 = ntload4(pl + 0), v1 = ntload4(pl + 1), v2 = ntload4(pl + 2),
             v3 = ntload4(pl + 3), v4 = ntload4(pl + 4), v5 = ntload4(pl + 5),
             v6 = ntload4(pl + 6), v7 = ntload4(pl + 7), v8 = ntload4(pl + 8),
             v9 = ntload4(pl + 9);
      // logits[i] layout: 8 heads x 5 classes, flattened in 40 floats.
      l0 = v0.x + v1.y + v2.z + v3.w + v5.x + v6.y + v7.z + v8.w;          // idx 0,5,10,15,20,25,30,35
      l1 = v0.y + v1.z + v2.w + v4.x + v5.y + v6.z + v7.w + v9.x;          // idx 1,6,11,16,21,26,31,36
      l2 = v0.z + v1.w + v3.x + v4.y + v5.z + v6.w + v8.x + v9.y;          // idx 2,7,12,17,22,27,32,37
      l3 = v0.w + v2.x + v3.y + v4.z + v5.w + v7.x + v8.y + v9.z;          // idx 3,8,13,18,23,28,33,38
      l4 = v1.x + v2.y + v3.z + v4.w + v6.x + v7.y + v8.z + v9.w;          // idx 4,9,14,19,24,29,34,39
    }
    l0 *= 0.125f; l1 *= 0.125f; l2 *= 0.125f; l3 *= 0.125f; l4 *= 0.125f;
    float mx = fmaxf(fmaxf(fmaxf(l0, l1), fmaxf(l2, l3)), l4);
    float se = __expf(l0 - mx) + __expf(l1 - mx) + __expf(l2 - mx) +
               __expf(l3 - mx) + __expf(l4 - mx);
    float lse = __logf(se) + mx;
    float lsel = (lb == 0) ? l0 : (lb == 1) ? l1 : (lb == 2) ? l2 : (lb == 3) ? l3 : l4;
    ce += lsel - lse;

    if (e > 0) {
      int b = (int)(d * (float)NB2);
      b = b < 0 ? 0 : (b > NB2 - 1 ? NB2 - 1 : b);
      float lg = __logf(suffix[(size_t)b * 4 + (e - 1)] + (float)EPS);
      lg0 += (e == 1) ? lg : 0.f;
      lg1 += (e == 2) ? lg : 0.f;
      lg2 += (e == 3) ? lg : 0.f;
      lg3 += (e == 4) ? lg : 0.f;
    }
  }

  WRED(ce) WRED(lg0) WRED(lg1) WRED(lg2) WRED(lg3)
  if ((t & 63) == 0) {
    atomicAdd(&s_f[0], lg0); atomicAdd(&s_f[1], lg1);
    atomicAdd(&s_f[2], lg2); atomicAdd(&s_f[3], lg3);
    atomicAdd(&s_f[4], ce);
  }
  __syncthreads();
  if (t < 4) unsafeAtomicAdd(&acc[4 + t], (double)s_f[t]);
  if (t == 4) unsafeAtomicAdd(&acc[8], (double)s_f[4]);

  // ---- fused finalize: last block to finish computes the scalar output ----
  // __syncthreads has vmcnt(0)-drain semantics -> this block's acc atomics
  // are complete at memory before the ticket increment below.
  __syncthreads();
  if (t == 0) {
    __threadfence();
    unsigned r = atomicAdd(ticket, 1u);
    if (r == gridDim.x - 1) {          // last block: all acc/cnt final
      __threadfence();
      double ls = 0.0;
      for (int c = 0; c < 4; ++c) {
        double s = acc[c] - acc[4 + c];
        ls += -s / ((double)cnt[c] + EPS);
      }
      double cem = -acc[8] / (double)N;
      out[0] = (float)(ALPHA * ls + (1.0 - ALPHA) * cem);
    }
  }
}

extern "C" void kernel_launch(void* const* d_in, const int* in_sizes, int n_in,
                              void* d_out, int out_size, void* d_ws, size_t ws_size,
                              hipStream_t stream) {
  const float* log_h  = (const float*)d_in[0];
  const float* logits = (const float*)d_in[1];
  const float* dur    = (const float*)d_in[2];
  const int*   ev     = (const int*)d_in[3];
  const int*   lab    = (const int*)d_in[4];
  const int N = in_sizes[2];

  const size_t cellBytes = (size_t)NCELL * sizeof(float);   // 32 KB
  char* ws = (char*)d_ws;
  double* acc = (double*)ws;
  unsigned int* cnt = (unsigned int*)(ws + 128);
  unsigned int* ticket = (unsigned int*)(ws + 192);
  float* partial = (float*)(ws + 4096);
  float* suffix  = (float*)(ws + 4096 + (size_t)NPART * cellBytes);

  // Zero header + the 8 atomic partial histograms (~260 KB); suffix is fully written.
  hipMemsetAsync(ws, 0, 4096 + (size_t)NPART * cellBytes, stream);

  cox_kernel<<<1024, 512, 0, stream>>>(log_h, dur, ev, partial, acc, cnt, N);
  scan_kernel<<<1, 1024, 0, stream>>>(partial, suffix);
  ce_kernel<<<2048, 256, 0, stream>>>(logits, lab, dur, ev, suffix, acc, cnt,
                                      ticket, (float*)d_out, N);
}

// Round 7
// 384.999 us; speedup vs baseline: 1.3405x; 1.3405x over previous
//
#include <hip/hip_runtime.h>
#include <cstdint>
#include <cstddef>

#define NB2 2048            // duration buckets (uniform [0,1))
#define NCELL (NB2 * 4)     // buckets x 4 causes
#define NPART 8             // one partial histogram per XCD-ish slice (blockIdx & 7)
#define ALPHA 0.4
#define EPS 1e-8

// Workspace layout:
//   [0,128)     double acc[9]: [0..3] sum eta over events/cause, [4..7] sum log(denom)/cause, [8] CE sum
//   [128,144)   uint cnt[4]
//   [192,196)   uint ticket (pass3 completion counter)
//   [4096, 4096+8*32KB)  float partial[8][NCELL] (AoS: [b*4+c]), atomically accumulated
//   then 32KB            float suffix[NCELL] (AoS)

#define WRED(v) { for (int o = 32; o; o >>= 1) v += __shfl_down(v, o); }

// ------- merged Cox + CE single pass (r0 item body, r1 occupancy config) -------
// 512 thr x 1024 blocks = 4 blocks/CU (32KB-LDS-capped) = 16 waves/CU.
// Scattered per-lane float4 loads, TEMPORAL (L3 absorbs ~50% -- measured r0/r6).
__global__ __launch_bounds__(512, 4) void pass1_kernel(
    const float* __restrict__ log_h, const float* __restrict__ logits,
    const float* __restrict__ dur, const int* __restrict__ ev,
    const int* __restrict__ lab, float* __restrict__ partial,
    double* __restrict__ acc, unsigned int* __restrict__ cnt, int N)
{
  __shared__ float h[NCELL];          // 32 KB private histogram, SoA
  __shared__ float s_f[5];
  __shared__ unsigned int s_u[4];
  const int t = threadIdx.x;
  for (int j = t; j < NCELL; j += 512) h[j] = 0.f;
  if (t < 5) s_f[t] = 0.f;
  if (t < 4) s_u[t] = 0u;
  __syncthreads();

  float ce = 0.f;
  float ea0 = 0.f, ea1 = 0.f, ea2 = 0.f, ea3 = 0.f;
  int c0 = 0, c1 = 0, c2 = 0, c3 = 0;

  const int stride = gridDim.x * 512;
  for (int i = blockIdx.x * 512 + t; i < N; i += stride) {
    // ---- eta = clip(mean over 8 heads, -50, 50); exp ----
    const float4* ph = (const float4*)(log_h + (size_t)i * 32);
    float m0 = 0.f, m1 = 0.f, m2 = 0.f, m3 = 0.f;
#pragma unroll
    for (int m = 0; m < 8; ++m) {
      float4 v = ph[m];
      m0 += v.x; m1 += v.y; m2 += v.z; m3 += v.w;
    }
    float e0 = fminf(fmaxf(m0 * 0.125f, -50.f), 50.f);
    float e1 = fminf(fmaxf(m1 * 0.125f, -50.f), 50.f);
    float e2 = fminf(fmaxf(m2 * 0.125f, -50.f), 50.f);
    float e3 = fminf(fmaxf(m3 * 0.125f, -50.f), 50.f);
    float x0 = __expf(e0), x1 = __expf(e1), x2 = __expf(e2), x3 = __expf(e3);

    float d = dur[i];
    int b = (int)(d * (float)NB2);
    b = b < 0 ? 0 : (b > NB2 - 1 ? NB2 - 1 : b);
    atomicAdd(&h[0 * NB2 + b], x0);   // SoA: bank = b%32, conflict-light
    atomicAdd(&h[1 * NB2 + b], x1);
    atomicAdd(&h[2 * NB2 + b], x2);
    atomicAdd(&h[3 * NB2 + b], x3);

    int e = ev[i];
    ea0 += (e == 1) ? e0 : 0.f;  c0 += (e == 1);
    ea1 += (e == 2) ? e1 : 0.f;  c1 += (e == 2);
    ea2 += (e == 3) ? e2 : 0.f;  c2 += (e == 3);
    ea3 += (e == 4) ? e3 : 0.f;  c3 += (e == 4);

    // ---- cross-entropy on mean logits ----
    const float4* pl = (const float4*)(logits + (size_t)i * 40);
    float buf[40];
#pragma unroll
    for (int j = 0; j < 10; ++j) ((float4*)buf)[j] = pl[j];
    float l0 = 0.f, l1 = 0.f, l2 = 0.f, l3 = 0.f, l4 = 0.f;
#pragma unroll
    for (int m = 0; m < 8; ++m) {
      l0 += buf[m * 5 + 0]; l1 += buf[m * 5 + 1]; l2 += buf[m * 5 + 2];
      l3 += buf[m * 5 + 3]; l4 += buf[m * 5 + 4];
    }
    l0 *= 0.125f; l1 *= 0.125f; l2 *= 0.125f; l3 *= 0.125f; l4 *= 0.125f;
    float mx = fmaxf(fmaxf(fmaxf(l0, l1), fmaxf(l2, l3)), l4);
    float se = __expf(l0 - mx) + __expf(l1 - mx) + __expf(l2 - mx) +
               __expf(l3 - mx) + __expf(l4 - mx);
    float lse = __logf(se) + mx;
    int lb = lab[i];
    float lsel = (lb == 0) ? l0 : (lb == 1) ? l1 : (lb == 2) ? l2 : (lb == 3) ? l3 : l4;
    ce += lsel - lse;
  }

  WRED(ea0) WRED(ea1) WRED(ea2) WRED(ea3) WRED(ce)
  WRED(c0) WRED(c1) WRED(c2) WRED(c3)
  if ((t & 63) == 0) {
    atomicAdd(&s_f[0], ea0); atomicAdd(&s_f[1], ea1);
    atomicAdd(&s_f[2], ea2); atomicAdd(&s_f[3], ea3);
    atomicAdd(&s_f[4], ce);
    atomicAdd(&s_u[0], (unsigned)c0); atomicAdd(&s_u[1], (unsigned)c1);
    atomicAdd(&s_u[2], (unsigned)c2); atomicAdd(&s_u[3], (unsigned)c3);
  }
  __syncthreads();

  // Flush LDS histogram (SoA) into partial[blockIdx&7] (AoS) with atomics.
  float* part = partial + (size_t)(blockIdx.x & (NPART - 1)) * NCELL;
  const int rot = ((blockIdx.x >> 3) & 31) * 256;
  for (int j = t; j < NCELL; j += 512) {
    int jj = (j + rot) & (NCELL - 1);
    float v = h[((jj & 3) << 11) + (jj >> 2)];   // SoA read -> AoS cell jj
    unsafeAtomicAdd(&part[jj], v);
  }

  if (t < 4) {
    unsafeAtomicAdd(&acc[t], (double)s_f[t]);
    atomicAdd(&cnt[t], s_u[t]);
  }
  if (t == 4) unsafeAtomicAdd(&acc[8], (double)s_f[4]);
}

// ---- Inclusive suffix-sum over NB2 buckets (4 causes packed as float4). ----
// Also folds the NPART partial histograms. One WG.
__global__ __launch_bounds__(1024) void scan_kernel(
    const float* __restrict__ partial, float* __restrict__ suffix)
{
  const int CH = NB2 / 1024;   // 2
  const int t = threadIdx.x;
  __shared__ float4 part[1024];
  float4* out = (float4*)suffix;

  float4 loc[CH];
  float4 a = make_float4(0.f, 0.f, 0.f, 0.f);
  for (int j = 0; j < CH; ++j) {
    float4 s = make_float4(0.f, 0.f, 0.f, 0.f);
#pragma unroll
    for (int p = 0; p < NPART; ++p) {
      float4 v = ((const float4*)(partial + (size_t)p * NCELL))[t * CH + j];
      s.x += v.x; s.y += v.y; s.z += v.z; s.w += v.w;
    }
    loc[j] = s;
    a.x += s.x; a.y += s.y; a.z += s.z; a.w += s.w;
  }
  part[t] = a;
  __syncthreads();
  for (int off = 1; off < 1024; off <<= 1) {
    float4 add = make_float4(0.f, 0.f, 0.f, 0.f);
    if (t + off < 1024) add = part[t + off];
    __syncthreads();
    float4 cur = part[t];
    cur.x += add.x; cur.y += add.y; cur.z += add.z; cur.w += add.w;
    part[t] = cur;
    __syncthreads();
  }
  float4 carry = (t < 1023) ? part[t + 1] : make_float4(0.f, 0.f, 0.f, 0.f);
  for (int j = CH - 1; j >= 0; --j) {
    carry.x += loc[j].x; carry.y += loc[j].y; carry.z += loc[j].z; carry.w += loc[j].w;
    out[t * CH + j] = carry;
  }
}

// ---- pass3: gather log(denom) per event + fused ticket finalize ----
// Reads dur/ev (8 MB) coalesced; suffix (32 KB) is L2/L3-resident.
__global__ __launch_bounds__(256, 8) void pass3_kernel(
    const float* __restrict__ dur, const int* __restrict__ ev,
    const float* __restrict__ suffix, double* __restrict__ acc,
    const unsigned int* __restrict__ cnt, unsigned int* __restrict__ ticket,
    float* __restrict__ out, int N)
{
  __shared__ float s_lg[4];
  const int t = threadIdx.x;
  if (t < 4) s_lg[t] = 0.f;
  __syncthreads();

  float lg0 = 0.f, lg1 = 0.f, lg2 = 0.f, lg3 = 0.f;
  const int stride = gridDim.x * 256;
  for (int i = blockIdx.x * 256 + t; i < N; i += stride) {
    int e = ev[i];
    if (e > 0) {
      float d = dur[i];
      int b = (int)(d * (float)NB2);
      b = b < 0 ? 0 : (b > NB2 - 1 ? NB2 - 1 : b);
      float lg = __logf(suffix[(size_t)b * 4 + (e - 1)] + (float)EPS);
      lg0 += (e == 1) ? lg : 0.f;
      lg1 += (e == 2) ? lg : 0.f;
      lg2 += (e == 3) ? lg : 0.f;
      lg3 += (e == 4) ? lg : 0.f;
    }
  }
  WRED(lg0) WRED(lg1) WRED(lg2) WRED(lg3)
  if ((t & 63) == 0) {
    atomicAdd(&s_lg[0], lg0); atomicAdd(&s_lg[1], lg1);
    atomicAdd(&s_lg[2], lg2); atomicAdd(&s_lg[3], lg3);
  }
  __syncthreads();
  if (t < 4) unsafeAtomicAdd(&acc[4 + t], (double)s_lg[t]);

  // ---- fused finalize (pattern validated r6: passed, absmax 0) ----
  __syncthreads();   // drains this block's global atomics (vmcnt 0 before barrier)
  if (t == 0) {
    __threadfence();
    unsigned r = atomicAdd(ticket, 1u);
    if (r == gridDim.x - 1) {          // last block: all acc/cnt final
      __threadfence();
      double ls = 0.0;
      for (int c = 0; c < 4; ++c) {
        double s = acc[c] - acc[4 + c];
        ls += -s / ((double)cnt[c] + EPS);
      }
      double cem = -acc[8] / (double)N;
      out[0] = (float)(ALPHA * ls + (1.0 - ALPHA) * cem);
    }
  }
}

extern "C" void kernel_launch(void* const* d_in, const int* in_sizes, int n_in,
                              void* d_out, int out_size, void* d_ws, size_t ws_size,
                              hipStream_t stream) {
  const float* log_h  = (const float*)d_in[0];
  const float* logits = (const float*)d_in[1];
  const float* dur    = (const float*)d_in[2];
  const int*   ev     = (const int*)d_in[3];
  const int*   lab    = (const int*)d_in[4];
  const int N = in_sizes[2];

  const size_t cellBytes = (size_t)NCELL * sizeof(float);   // 32 KB
  char* ws = (char*)d_ws;
  double* acc = (double*)ws;
  unsigned int* cnt = (unsigned int*)(ws + 128);
  unsigned int* ticket = (unsigned int*)(ws + 192);
  float* partial = (float*)(ws + 4096);
  float* suffix  = (float*)(ws + 4096 + (size_t)NPART * cellBytes);

  // Zero header + the 8 atomic partial histograms (~260 KB); suffix is fully written.
  hipMemsetAsync(ws, 0, 4096 + (size_t)NPART * cellBytes, stream);

  pass1_kernel<<<1024, 512, 0, stream>>>(log_h, logits, dur, ev, lab,
                                         partial, acc, cnt, N);
  scan_kernel<<<1, 1024, 0, stream>>>(partial, suffix);
  pass3_kernel<<<2048, 256, 0, stream>>>(dur, ev, suffix, acc, cnt, ticket,
                                         (float*)d_out, N);
}